// Round 3
// baseline (15351.398 us; speedup 1.0000x reference)
//
#include <hip/hip_runtime.h>
#include <hip/hip_bf16.h>
#include <cstdint>

// LSTM B=256 T=512 F=256 H=512 — persistent cooperative kernel (round 3).
// 256 blocks x 256 threads (4 waves). Group = 32 blocks sharing rg (32 batch
// rows); rg = bid&7 -> group is XCD-local under round-robin dispatch
// (heuristic; correctness via agent-scope atomics + fences only).
// Block covers 4 gates x 16 h-cols. Waves: (wc = gate pair, wk = K half).
// Weights: bf16 B-fragments in REGISTERS (96 VGPR/wave). Per step:
// A=[x_t | h_{t-1}] staged in LDS (bf16), 16x16x32 MFMA, split-K reduce via
// LDS, fused gates, c in registers, h -> out (f32) + hbuf (bf16, DOUBLE-
// BUFFERED by t-parity: fixes WAR race of round 2). Consumers issue an
// agent-scope acquire fence (buffer_inv) before reading hbuf: fixes stale-L1.
// ws: BT 3MB @0 | bar 2KB @0x300000 | hbuf[2] 512KB @0x300800.

#define B_   256
#define T_   512
#define F_   256
#define H_   512
#define K_   768
#define NG_  2048
#define AW   776   // K_ + 8 bf16 pad

typedef __attribute__((ext_vector_type(8))) short short8;
typedef __attribute__((ext_vector_type(4))) float f32x4;

static __device__ __forceinline__ unsigned short f2bf(float f) {
  union { float f; unsigned u; } v; v.f = f;
  unsigned r = v.u + 0x7FFFu + ((v.u >> 16) & 1u);   // RNE
  return (unsigned short)(r >> 16);
}

__global__ void prep_weights(const float* __restrict__ Wi, const float* __restrict__ Wf,
                             const float* __restrict__ Wo, const float* __restrict__ Wc,
                             const float* __restrict__ Ui, const float* __restrict__ Uf,
                             const float* __restrict__ Uo, const float* __restrict__ Uc,
                             unsigned short* __restrict__ BT,
                             unsigned* __restrict__ bar) {
  if (blockIdx.x == 0 && threadIdx.x < 8) bar[threadIdx.x * 64] = 0u;  // reset per call
  int idx = blockIdx.x * 256 + threadIdx.x;
  if (idx >= NG_ * K_) return;
  int col = idx / K_;
  int k   = idx - col * K_;
  int gate = col >> 9;       // 0:i 1:f 2:o 3:c (reference concat order)
  int hc   = col & 511;
  const float* Wg = (gate == 0) ? Wi : (gate == 1) ? Wf : (gate == 2) ? Wo : Wc;
  const float* Ug = (gate == 0) ? Ui : (gate == 1) ? Uf : (gate == 2) ? Uo : Uc;
  float v = (k < F_) ? Wg[k * H_ + hc] : Ug[(k - F_) * H_ + hc];
  BT[idx] = f2bf(v);
}

__global__ __launch_bounds__(256, 1)
void lstm_persist(const float* __restrict__ x,
                  const unsigned short* __restrict__ BT,
                  const float* __restrict__ bi, const float* __restrict__ bfp,
                  const float* __restrict__ bo, const float* __restrict__ bc,
                  float* __restrict__ out,
                  unsigned* __restrict__ bar,
                  unsigned short* __restrict__ hbuf) {
  __shared__ __align__(16) unsigned short Ash[32][AW];
  __shared__ float Gsh[2][4][32][16];

  const int tid = threadIdx.x;
  const int rg = blockIdx.x & 7;     // group (32 rows), XCD-local heuristic
  const int cg = blockIdx.x >> 3;    // 16 h-cols strip
  const int wave = tid >> 6, lane = tid & 63;
  const int wc = wave & 1, wk = wave >> 1;
  const int l15 = lane & 15, l4 = lane >> 4;

  // ---- persistent B fragments: 2 gate-strips x 12 k-chunks = 96 VGPRs ----
  short8 Breg0[12], Breg1[12];
  {
    const unsigned short* Bp0 =
        BT + (size_t)(((wc * 2 + 0) << 9) | (cg << 4) | l15) * K_ + wk * 384 + l4 * 8;
    const unsigned short* Bp1 =
        BT + (size_t)(((wc * 2 + 1) << 9) | (cg << 4) | l15) * K_ + wk * 384 + l4 * 8;
    #pragma unroll
    for (int kk = 0; kk < 12; ++kk) {
      Breg0[kk] = *reinterpret_cast<const short8*>(Bp0 + kk * 32);
      Breg1[kk] = *reinterpret_cast<const short8*>(Bp1 + kk * 32);
    }
  }

  // ---- gate-math thread mapping: 2 outputs (row, hc0..hc0+1) ----
  const int grow_r = tid >> 3;             // 0..31
  const int gcol0 = (tid & 7) * 2;         // 0..14 even
  const int hcg = (cg << 4) + gcol0;       // global h col
  const float bi0 = bi[hcg],  bi1 = bi[hcg + 1];
  const float bf0 = bfp[hcg], bf1 = bfp[hcg + 1];
  const float bo0 = bo[hcg],  bo1 = bo[hcg + 1];
  const float bc0 = bc[hcg],  bc1 = bc[hcg + 1];
  float cc0 = 0.f, cc1 = 0.f;              // cell state in registers
  const int grow = rg * 32 + grow_r;
  float* outp = out + (size_t)grow * T_ * H_ + hcg;
  // double-buffered h broadcast: parity p holds h(t) for t&1==p
  unsigned* hbp0 = reinterpret_cast<unsigned*>(hbuf + (size_t)grow * H_ + hcg);
  unsigned* hbp1 = reinterpret_cast<unsigned*>(hbuf + (size_t)(B_ + grow) * H_ + hcg);

  // ---- stage x(0) ----
  #pragma unroll
  for (int j = 0; j < 8; ++j) {
    int f = tid + 256 * j; int row = f >> 6, k4 = f & 63;
    const float4 v = *reinterpret_cast<const float4*>(
        x + (size_t)(rg * 32 + row) * T_ * F_ + k4 * 4);
    ushort4 s; s.x = f2bf(v.x); s.y = f2bf(v.y); s.z = f2bf(v.z); s.w = f2bf(v.w);
    *reinterpret_cast<ushort4*>(&Ash[row][k4 * 4]) = s;
  }

  unsigned* cnt = &bar[rg * 64];
  const int abase = wk * 384 + l4 * 8;

  for (int t = 0; t < T_; ++t) {
    // ---- stage h(t-1) from parity (t-1)&1 buffer (zeros at t=0) ----
    if (t > 0) {
      // invalidate L1 so we observe peer blocks' stores (agent acquire)
      __builtin_amdgcn_fence(__ATOMIC_ACQUIRE, "agent");
      const unsigned short* hsrc = hbuf + (size_t)(((t - 1) & 1) ? B_ : 0) * H_;
      #pragma unroll
      for (int j = 0; j < 8; ++j) {
        int f = tid + 256 * j; int row = f >> 6, c8 = f & 63;   // 32 x 64 chunks
        short8 v = *reinterpret_cast<const short8*>(
            hsrc + (size_t)(rg * 32 + row) * H_ + c8 * 8);
        *reinterpret_cast<short8*>(&Ash[row][F_ + c8 * 8]) = v;
      }
    } else {
      #pragma unroll
      for (int j = 0; j < 8; ++j) {
        int f = tid + 256 * j; int row = f >> 6, c8 = f & 63;
        short8 z = {0,0,0,0,0,0,0,0};
        *reinterpret_cast<short8*>(&Ash[row][F_ + c8 * 8]) = z;
      }
    }
    __syncthreads();                                   // B1

    // ---- MFMA: 32 rows x 32 cols x 384 K per wave ----
    f32x4 acc00 = {0,0,0,0}, acc10 = {0,0,0,0}, acc01 = {0,0,0,0}, acc11 = {0,0,0,0};
    #pragma unroll
    for (int kk = 0; kk < 12; ++kk) {
      const short8 a0 = *reinterpret_cast<const short8*>(&Ash[l15][abase + kk * 32]);
      const short8 a1 = *reinterpret_cast<const short8*>(&Ash[16 + l15][abase + kk * 32]);
      acc00 = __builtin_amdgcn_mfma_f32_16x16x32_bf16(a0, Breg0[kk], acc00, 0, 0, 0);
      acc10 = __builtin_amdgcn_mfma_f32_16x16x32_bf16(a1, Breg0[kk], acc10, 0, 0, 0);
      acc01 = __builtin_amdgcn_mfma_f32_16x16x32_bf16(a0, Breg1[kk], acc01, 0, 0, 0);
      acc11 = __builtin_amdgcn_mfma_f32_16x16x32_bf16(a1, Breg1[kk], acc11, 0, 0, 0);
    }
    #pragma unroll
    for (int r = 0; r < 4; ++r) {                      // D: col=l15, row=l4*4+r
      Gsh[wk][wc * 2 + 0][l4 * 4 + r][l15]      = acc00[r];
      Gsh[wk][wc * 2 + 0][16 + l4 * 4 + r][l15] = acc10[r];
      Gsh[wk][wc * 2 + 1][l4 * 4 + r][l15]      = acc01[r];
      Gsh[wk][wc * 2 + 1][16 + l4 * 4 + r][l15] = acc11[r];
    }
    __syncthreads();                                   // B2

    // ---- prefetch x(t+1) into regs (overlaps gate math + barrier) ----
    float4 xv[8];
    if (t + 1 < T_) {
      #pragma unroll
      for (int j = 0; j < 8; ++j) {
        int f = tid + 256 * j; int row = f >> 6, k4 = f & 63;
        xv[j] = *reinterpret_cast<const float4*>(
            x + ((size_t)(rg * 32 + row) * T_ + (t + 1)) * F_ + k4 * 4);
      }
    }

    // ---- fused gates + cell update ----
    {
      const float gi0 = Gsh[0][0][grow_r][gcol0] + Gsh[1][0][grow_r][gcol0] + bi0;
      const float gi1 = Gsh[0][0][grow_r][gcol0+1] + Gsh[1][0][grow_r][gcol0+1] + bi1;
      const float gf0 = Gsh[0][1][grow_r][gcol0] + Gsh[1][1][grow_r][gcol0] + bf0;
      const float gf1 = Gsh[0][1][grow_r][gcol0+1] + Gsh[1][1][grow_r][gcol0+1] + bf1;
      const float go0 = Gsh[0][2][grow_r][gcol0] + Gsh[1][2][grow_r][gcol0] + bo0;
      const float go1 = Gsh[0][2][grow_r][gcol0+1] + Gsh[1][2][grow_r][gcol0+1] + bo1;
      const float gc0 = Gsh[0][3][grow_r][gcol0] + Gsh[1][3][grow_r][gcol0] + bc0;
      const float gc1 = Gsh[0][3][grow_r][gcol0+1] + Gsh[1][3][grow_r][gcol0+1] + bc1;
      const float it0 = 1.f / (1.f + __expf(-gi0)), it1 = 1.f / (1.f + __expf(-gi1));
      const float ft0 = 1.f / (1.f + __expf(-gf0)), ft1 = 1.f / (1.f + __expf(-gf1));
      const float ot0 = 1.f / (1.f + __expf(-go0)), ot1 = 1.f / (1.f + __expf(-go1));
      const float ct0 = tanhf(gc0), ct1 = tanhf(gc1);
      cc0 = ft0 * cc0 + it0 * ct0;
      cc1 = ft1 * cc1 + it1 * ct1;
      const float h0 = ot0 * tanhf(cc0);
      const float h1 = ot1 * tanhf(cc1);
      float2 hw; hw.x = h0; hw.y = h1;
      *reinterpret_cast<float2*>(outp + (size_t)t * H_) = hw;          // output
      unsigned hp = (unsigned)f2bf(h0) | ((unsigned)f2bf(h1) << 16);
      if (t & 1) *hbp1 = hp; else *hbp0 = hp;          // parity t&1 buffer
    }

    // ---- write prefetched x(t+1) to LDS ----
    if (t + 1 < T_) {
      #pragma unroll
      for (int j = 0; j < 8; ++j) {
        int f = tid + 256 * j; int row = f >> 6, k4 = f & 63;
        ushort4 s; s.x = f2bf(xv[j].x); s.y = f2bf(xv[j].y);
        s.z = f2bf(xv[j].z); s.w = f2bf(xv[j].w);
        *reinterpret_cast<ushort4*>(&Ash[row][k4 * 4]) = s;
      }
    }

    // ---- group barrier: 32 blocks of rg ----
    __builtin_amdgcn_fence(__ATOMIC_RELEASE, "agent");   // drain h stores to L2
    __syncthreads();                                     // B3
    if (tid == 0) {
      __hip_atomic_fetch_add(cnt, 1u, __ATOMIC_RELEASE, __HIP_MEMORY_SCOPE_AGENT);
      const unsigned tgt = 32u * (unsigned)(t + 1);
      while (__hip_atomic_load(cnt, __ATOMIC_ACQUIRE, __HIP_MEMORY_SCOPE_AGENT) < tgt)
        __builtin_amdgcn_s_sleep(8);
    }
    __syncthreads();                                     // B4
  }
}

extern "C" void kernel_launch(void* const* d_in, const int* in_sizes, int n_in,
                              void* d_out, int out_size, void* d_ws, size_t ws_size,
                              hipStream_t stream) {
  const float* x  = (const float*)d_in[0];
  const float* Wi = (const float*)d_in[1];
  const float* Ui = (const float*)d_in[2];
  const float* bi = (const float*)d_in[3];
  const float* Wf = (const float*)d_in[4];
  const float* Uf = (const float*)d_in[5];
  const float* bf = (const float*)d_in[6];
  const float* Wc = (const float*)d_in[7];
  const float* Uc = (const float*)d_in[8];
  const float* bc = (const float*)d_in[9];
  const float* Wo = (const float*)d_in[10];
  const float* Uo = (const float*)d_in[11];
  const float* bo = (const float*)d_in[12];
  float* out = (float*)d_out;

  unsigned short* BT = (unsigned short*)d_ws;                         // 3 MB
  unsigned* bar = (unsigned*)((char*)d_ws + 0x300000);                // 2 KB
  unsigned short* hbuf = (unsigned short*)((char*)d_ws + 0x300800);   // 512 KB (x2)

  prep_weights<<<(NG_ * K_ + 255) / 256, 256, 0, stream>>>(
      Wi, Wf, Wo, Wc, Ui, Uf, Uo, Uc, BT, bar);

  void* args[] = {(void*)&x, (void*)&BT, (void*)&bi, (void*)&bf, (void*)&bo,
                  (void*)&bc, (void*)&out, (void*)&bar, (void*)&hbuf};
  hipLaunchCooperativeKernel(reinterpret_cast<const void*>(&lstm_persist),
                             dim3(256), dim3(256), args, 0, stream);
}

// Round 4
// 1871.346 us; speedup vs baseline: 8.2034x; 8.2034x over previous
//
#include <hip/hip_runtime.h>
#include <hip/hip_bf16.h>
#include <cstdint>

// LSTM B=256 T=512 F=256 H=512 — persistent kernel, round 4.
// Round-3 lesson: agent-scope fences = per-step L2 writeback+invalidate
// (30us/step). Round 4: ZERO fences. Cross-XCD h exchange + group barrier go
// through cache-BYPASSING accesses (sc0 sc1 -> memory-side Infinity Cache,
// coherent across XCDs). Barrier = 32 per-block flags (store t+1 after
// __syncthreads drain), consumers spin-poll one flag per thread. Weights stay
// in registers; numeric path identical to round 3 (absmax 7.4e-3).
// ws: BT 3MB @0 | hbuf[2] 512KB @0x300000 | flags 16KB @0x380000.

#define B_   256
#define T_   512
#define F_   256
#define H_   512
#define K_   768
#define NG_  2048
#define AW   776   // K_ + 8 bf16 pad

typedef __attribute__((ext_vector_type(8))) short short8;
typedef __attribute__((ext_vector_type(4))) float f32x4;

static __device__ __forceinline__ unsigned short f2bf(float f) {
  union { float f; unsigned u; } v; v.f = f;
  unsigned r = v.u + 0x7FFFu + ((v.u >> 16) & 1u);   // RNE
  return (unsigned short)(r >> 16);
}

__global__ void prep_weights(const float* __restrict__ Wi, const float* __restrict__ Wf,
                             const float* __restrict__ Wo, const float* __restrict__ Wc,
                             const float* __restrict__ Ui, const float* __restrict__ Uf,
                             const float* __restrict__ Uo, const float* __restrict__ Uc,
                             unsigned short* __restrict__ BT,
                             unsigned* __restrict__ flags) {
  if (blockIdx.x == 0) {                      // re-zero flags every call (sc1:
    unsigned* fp = flags + threadIdx.x * 16;  // visible to bypassing readers)
    unsigned z = 0;
    asm volatile("global_store_dword %0, %1, off sc0 sc1" :: "v"(fp), "v"(z) : "memory");
  }
  int idx = blockIdx.x * 256 + threadIdx.x;
  if (idx >= NG_ * K_) return;
  int col = idx / K_;
  int k   = idx - col * K_;
  int gate = col >> 9;       // 0:i 1:f 2:o 3:c (reference concat order)
  int hc   = col & 511;
  const float* Wg = (gate == 0) ? Wi : (gate == 1) ? Wf : (gate == 2) ? Wo : Wc;
  const float* Ug = (gate == 0) ? Ui : (gate == 1) ? Uf : (gate == 2) ? Uo : Uc;
  float v = (k < F_) ? Wg[k * H_ + hc] : Ug[(k - F_) * H_ + hc];
  BT[idx] = f2bf(v);
}

__global__ __launch_bounds__(256, 1)
void lstm_persist(const float* __restrict__ x,
                  const unsigned short* __restrict__ BT,
                  const float* __restrict__ bi, const float* __restrict__ bfp,
                  const float* __restrict__ bo, const float* __restrict__ bc,
                  float* __restrict__ out,
                  unsigned* __restrict__ flags,
                  unsigned short* __restrict__ hbuf) {
  __shared__ __align__(16) unsigned short Ash[32][AW];
  __shared__ float Gsh[2][4][32][16];

  const int tid = threadIdx.x;
  const int rg = blockIdx.x & 7;     // group (32 rows)
  const int cg = blockIdx.x >> 3;    // 16 h-cols strip (= flag slot)
  const int wave = tid >> 6, lane = tid & 63;
  const int wc = wave & 1, wk = wave >> 1;
  const int l15 = lane & 15, l4 = lane >> 4;

  // ---- persistent B fragments: 2 gate-strips x 12 k-chunks = 96 VGPRs ----
  short8 Breg0[12], Breg1[12];
  {
    const unsigned short* Bp0 =
        BT + (size_t)(((wc * 2 + 0) << 9) | (cg << 4) | l15) * K_ + wk * 384 + l4 * 8;
    const unsigned short* Bp1 =
        BT + (size_t)(((wc * 2 + 1) << 9) | (cg << 4) | l15) * K_ + wk * 384 + l4 * 8;
    #pragma unroll
    for (int kk = 0; kk < 12; ++kk) {
      Breg0[kk] = *reinterpret_cast<const short8*>(Bp0 + kk * 32);
      Breg1[kk] = *reinterpret_cast<const short8*>(Bp1 + kk * 32);
    }
  }

  // ---- gate-math thread mapping: 2 outputs (row, hc0..hc0+1) ----
  const int grow_r = tid >> 3;             // 0..31
  const int gcol0 = (tid & 7) * 2;         // 0..14 even
  const int hcg = (cg << 4) + gcol0;       // global h col
  const float bi0 = bi[hcg],  bi1 = bi[hcg + 1];
  const float bf0 = bfp[hcg], bf1 = bfp[hcg + 1];
  const float bo0 = bo[hcg],  bo1 = bo[hcg + 1];
  const float bc0 = bc[hcg],  bc1 = bc[hcg + 1];
  float cc0 = 0.f, cc1 = 0.f;              // cell state in registers
  const int grow = rg * 32 + grow_r;
  float* outp = out + (size_t)grow * T_ * H_ + hcg;
  unsigned* hbp0 = reinterpret_cast<unsigned*>(hbuf + (size_t)grow * H_ + hcg);
  unsigned* hbp1 = reinterpret_cast<unsigned*>(hbuf + (size_t)(B_ + grow) * H_ + hcg);

  // ---- stage x(0) ----
  #pragma unroll
  for (int j = 0; j < 8; ++j) {
    int f = tid + 256 * j; int row = f >> 6, k4 = f & 63;
    const float4 v = *reinterpret_cast<const float4*>(
        x + (size_t)(rg * 32 + row) * T_ * F_ + k4 * 4);
    ushort4 s; s.x = f2bf(v.x); s.y = f2bf(v.y); s.z = f2bf(v.z); s.w = f2bf(v.w);
    *reinterpret_cast<ushort4*>(&Ash[row][k4 * 4]) = s;
  }

  const int abase = wk * 384 + l4 * 8;
  unsigned* myflag = flags + (rg * 32 + cg) * 16;
  const unsigned* pollflag = flags + (rg * 32 + (tid & 31)) * 16;

  for (int t = 0; t < T_; ++t) {
    // ---- stage h(t-1): L2-bypassing loads from parity buffer (IF$) ----
    if (t > 0) {
      const unsigned short* hsrc = hbuf + (size_t)(((t - 1) & 1) ? B_ : 0) * H_;
      // per thread: rows wave+4j (j=0..7), 16B at col lane*8
      unsigned vo = (unsigned)(((rg * 32 + wave) * H_ + lane * 8) * 2);
      short8 h0, h1, h2, h3, h4, h5, h6, h7;
      asm volatile(
        "global_load_dwordx4 %0, %8, %16 sc0 sc1\n\t"
        "global_load_dwordx4 %1, %9, %16 sc0 sc1\n\t"
        "global_load_dwordx4 %2, %10, %16 sc0 sc1\n\t"
        "global_load_dwordx4 %3, %11, %16 sc0 sc1\n\t"
        "global_load_dwordx4 %4, %12, %16 sc0 sc1\n\t"
        "global_load_dwordx4 %5, %13, %16 sc0 sc1\n\t"
        "global_load_dwordx4 %6, %14, %16 sc0 sc1\n\t"
        "global_load_dwordx4 %7, %15, %16 sc0 sc1\n\t"
        "s_waitcnt vmcnt(0)"
        : "=&v"(h0), "=&v"(h1), "=&v"(h2), "=&v"(h3),
          "=&v"(h4), "=&v"(h5), "=&v"(h6), "=&v"(h7)
        : "v"(vo), "v"(vo + 4096u), "v"(vo + 8192u), "v"(vo + 12288u),
          "v"(vo + 16384u), "v"(vo + 20480u), "v"(vo + 24576u), "v"(vo + 28672u),
          "s"(hsrc)
        : "memory");
      *reinterpret_cast<short8*>(&Ash[wave +  0][F_ + lane * 8]) = h0;
      *reinterpret_cast<short8*>(&Ash[wave +  4][F_ + lane * 8]) = h1;
      *reinterpret_cast<short8*>(&Ash[wave +  8][F_ + lane * 8]) = h2;
      *reinterpret_cast<short8*>(&Ash[wave + 12][F_ + lane * 8]) = h3;
      *reinterpret_cast<short8*>(&Ash[wave + 16][F_ + lane * 8]) = h4;
      *reinterpret_cast<short8*>(&Ash[wave + 20][F_ + lane * 8]) = h5;
      *reinterpret_cast<short8*>(&Ash[wave + 24][F_ + lane * 8]) = h6;
      *reinterpret_cast<short8*>(&Ash[wave + 28][F_ + lane * 8]) = h7;
    } else {
      #pragma unroll
      for (int j = 0; j < 8; ++j) {
        int f = tid + 256 * j; int row = f >> 6, c8 = f & 63;
        short8 z = {0, 0, 0, 0, 0, 0, 0, 0};
        *reinterpret_cast<short8*>(&Ash[row][F_ + c8 * 8]) = z;
      }
    }
    __syncthreads();                                   // B1

    // ---- MFMA: 32 rows x 32 cols x 384 K per wave ----
    f32x4 acc00 = {0,0,0,0}, acc10 = {0,0,0,0}, acc01 = {0,0,0,0}, acc11 = {0,0,0,0};
    #pragma unroll
    for (int kk = 0; kk < 12; ++kk) {
      const short8 a0 = *reinterpret_cast<const short8*>(&Ash[l15][abase + kk * 32]);
      const short8 a1 = *reinterpret_cast<const short8*>(&Ash[16 + l15][abase + kk * 32]);
      acc00 = __builtin_amdgcn_mfma_f32_16x16x32_bf16(a0, Breg0[kk], acc00, 0, 0, 0);
      acc10 = __builtin_amdgcn_mfma_f32_16x16x32_bf16(a1, Breg0[kk], acc10, 0, 0, 0);
      acc01 = __builtin_amdgcn_mfma_f32_16x16x32_bf16(a0, Breg1[kk], acc01, 0, 0, 0);
      acc11 = __builtin_amdgcn_mfma_f32_16x16x32_bf16(a1, Breg1[kk], acc11, 0, 0, 0);
    }
    #pragma unroll
    for (int r = 0; r < 4; ++r) {                      // D: col=l15, row=l4*4+r
      Gsh[wk][wc * 2 + 0][l4 * 4 + r][l15]      = acc00[r];
      Gsh[wk][wc * 2 + 0][16 + l4 * 4 + r][l15] = acc10[r];
      Gsh[wk][wc * 2 + 1][l4 * 4 + r][l15]      = acc01[r];
      Gsh[wk][wc * 2 + 1][16 + l4 * 4 + r][l15] = acc11[r];
    }
    __syncthreads();                                   // B2

    // ---- prefetch x(t+1) into regs (overlaps gate math) ----
    float4 xv[8];
    if (t + 1 < T_) {
      #pragma unroll
      for (int j = 0; j < 8; ++j) {
        int f = tid + 256 * j; int row = f >> 6, k4 = f & 63;
        xv[j] = *reinterpret_cast<const float4*>(
            x + ((size_t)(rg * 32 + row) * T_ + (t + 1)) * F_ + k4 * 4);
      }
    }

    // ---- fused gates + cell update ----
    {
      const float gi0 = Gsh[0][0][grow_r][gcol0] + Gsh[1][0][grow_r][gcol0] + bi0;
      const float gi1 = Gsh[0][0][grow_r][gcol0+1] + Gsh[1][0][grow_r][gcol0+1] + bi1;
      const float gf0 = Gsh[0][1][grow_r][gcol0] + Gsh[1][1][grow_r][gcol0] + bf0;
      const float gf1 = Gsh[0][1][grow_r][gcol0+1] + Gsh[1][1][grow_r][gcol0+1] + bf1;
      const float go0 = Gsh[0][2][grow_r][gcol0] + Gsh[1][2][grow_r][gcol0] + bo0;
      const float go1 = Gsh[0][2][grow_r][gcol0+1] + Gsh[1][2][grow_r][gcol0+1] + bo1;
      const float gc0 = Gsh[0][3][grow_r][gcol0] + Gsh[1][3][grow_r][gcol0] + bc0;
      const float gc1 = Gsh[0][3][grow_r][gcol0+1] + Gsh[1][3][grow_r][gcol0+1] + bc1;
      const float it0 = 1.f / (1.f + __expf(-gi0)), it1 = 1.f / (1.f + __expf(-gi1));
      const float ft0 = 1.f / (1.f + __expf(-gf0)), ft1 = 1.f / (1.f + __expf(-gf1));
      const float ot0 = 1.f / (1.f + __expf(-go0)), ot1 = 1.f / (1.f + __expf(-go1));
      const float ct0 = tanhf(gc0), ct1 = tanhf(gc1);
      cc0 = ft0 * cc0 + it0 * ct0;
      cc1 = ft1 * cc1 + it1 * ct1;
      const float h0 = ot0 * tanhf(cc0);
      const float h1 = ot1 * tanhf(cc1);
      float2 hw; hw.x = h0; hw.y = h1;
      *reinterpret_cast<float2*>(outp + (size_t)t * H_) = hw;          // output
      unsigned hp = (unsigned)f2bf(h0) | ((unsigned)f2bf(h1) << 16);
      unsigned* hq = (t & 1) ? hbp1 : hbp0;            // parity t&1 buffer
      asm volatile("global_store_dword %0, %1, off sc0 sc1"
                   :: "v"(hq), "v"(hp) : "memory");    // bypass -> IF$
    }

    // ---- write prefetched x(t+1) to LDS ----
    if (t + 1 < T_) {
      #pragma unroll
      for (int j = 0; j < 8; ++j) {
        int f = tid + 256 * j; int row = f >> 6, k4 = f & 63;
        ushort4 s; s.x = f2bf(xv[j].x); s.y = f2bf(xv[j].y);
        s.z = f2bf(xv[j].z); s.w = f2bf(xv[j].w);
        *reinterpret_cast<ushort4*>(&Ash[row][k4 * 4]) = s;
      }
    }

    // ---- group barrier (no fences, no atomics) ----
    asm volatile("s_waitcnt vmcnt(0)" ::: "memory");   // h stores acked at IF$
    __syncthreads();                                   // B3: whole block done
    if (tid == 0) {                                    // publish "step t done"
      unsigned val = (unsigned)(t + 1);
      asm volatile("global_store_dword %0, %1, off sc0 sc1"
                   :: "v"(myflag), "v"(val) : "memory");
    }
    {                                                  // wait all 32 peers
      const unsigned want = (unsigned)(t + 1);
      if (tid < 32) {
        unsigned cur;
        do {
          asm volatile("global_load_dword %0, %1, off sc0 sc1\n\ts_waitcnt vmcnt(0)"
                       : "=v"(cur) : "v"(pollflag) : "memory");
        } while (cur < want);
      }
      __syncthreads();                                 // B4
    }
  }
}

extern "C" void kernel_launch(void* const* d_in, const int* in_sizes, int n_in,
                              void* d_out, int out_size, void* d_ws, size_t ws_size,
                              hipStream_t stream) {
  const float* x  = (const float*)d_in[0];
  const float* Wi = (const float*)d_in[1];
  const float* Ui = (const float*)d_in[2];
  const float* bi = (const float*)d_in[3];
  const float* Wf = (const float*)d_in[4];
  const float* Uf = (const float*)d_in[5];
  const float* bf = (const float*)d_in[6];
  const float* Wc = (const float*)d_in[7];
  const float* Uc = (const float*)d_in[8];
  const float* bc = (const float*)d_in[9];
  const float* Wo = (const float*)d_in[10];
  const float* Uo = (const float*)d_in[11];
  const float* bo = (const float*)d_in[12];
  float* out = (float*)d_out;

  unsigned short* BT = (unsigned short*)d_ws;                          // 3 MB
  unsigned short* hbuf = (unsigned short*)((char*)d_ws + 0x300000);    // 512 KB
  unsigned* flags = (unsigned*)((char*)d_ws + 0x380000);               // 16 KB

  prep_weights<<<(NG_ * K_ + 255) / 256, 256, 0, stream>>>(
      Wi, Wf, Wo, Wc, Ui, Uf, Uo, Uc, BT, flags);

  void* args[] = {(void*)&x, (void*)&BT, (void*)&bi, (void*)&bf, (void*)&bo,
                  (void*)&bc, (void*)&out, (void*)&flags, (void*)&hbuf};
  hipLaunchCooperativeKernel(reinterpret_cast<const void*>(&lstm_persist),
                             dim3(256), dim3(256), args, 0, stream);
}

// Round 5
// 1482.968 us; speedup vs baseline: 10.3518x; 1.2619x over previous
//
#include <hip/hip_runtime.h>
#include <hip/hip_bf16.h>
#include <cstdint>

// LSTM B=256 T=512 F=256 H=512 — persistent kernel, round 5.
// Round-4 was sync-latency-bound (3.65us/step). Round-5 shortens the serial
// chain: (1) out-store + x-convert moved AFTER flag publish (overlap peer
// flag propagation); (2) per-thread fused poll+stage (each thread's h chunk
// comes from exactly one peer = lane>>1; poll that flag then load) — one
// barrier removed, skew paid once; (3) no split-K: wave = gate, full K=768
// (half the Gsh traffic, no partial adds); (4) fast sigmoid/tanh via
// __expf + v_rcp; (5) Gsh [32][18] pad + float2 reads (bank conflicts).
// Sync fabric unchanged from round 4 (proven): sc0 sc1 cache-bypassing
// stores/loads through IF$ (cross-XCD coherent), per-block monotone flags.
// ws: BT 3MB @0 | hbuf[2] 512KB @0x300000 | flags 16KB @0x380000.

#define B_   256
#define T_   512
#define F_   256
#define H_   512
#define K_   768
#define NG_  2048
#define AW   776   // K_ + 8 bf16 pad

typedef __attribute__((ext_vector_type(8))) short short8;
typedef __attribute__((ext_vector_type(4))) float f32x4;

#define LOG2E 1.4426950408889634f

static __device__ __forceinline__ unsigned short f2bf(float f) {
  union { float f; unsigned u; } v; v.f = f;
  unsigned r = v.u + 0x7FFFu + ((v.u >> 16) & 1u);   // RNE
  return (unsigned short)(r >> 16);
}
static __device__ __forceinline__ float sigmoid_f(float x) {
  return __builtin_amdgcn_rcpf(1.f + __expf(-x));
}
static __device__ __forceinline__ float tanh_f(float x) {
  // tanh(x) = 1 - 2/(e^{2x}+1); inf/0 limits give +-1 correctly
  return 1.f - 2.f * __builtin_amdgcn_rcpf(__expf(2.f * x) + 1.f);
}

__global__ void prep_weights(const float* __restrict__ Wi, const float* __restrict__ Wf,
                             const float* __restrict__ Wo, const float* __restrict__ Wc,
                             const float* __restrict__ Ui, const float* __restrict__ Uf,
                             const float* __restrict__ Uo, const float* __restrict__ Uc,
                             unsigned short* __restrict__ BT,
                             unsigned* __restrict__ flags) {
  if (blockIdx.x == 0) {                      // re-zero flags every call
    unsigned* fp = flags + threadIdx.x * 16;
    unsigned z = 0;
    asm volatile("global_store_dword %0, %1, off sc0 sc1" :: "v"(fp), "v"(z) : "memory");
  }
  int idx = blockIdx.x * 256 + threadIdx.x;
  if (idx >= NG_ * K_) return;
  int col = idx / K_;
  int k   = idx - col * K_;
  int gate = col >> 9;       // 0:i 1:f 2:o 3:c (reference concat order)
  int hc   = col & 511;
  const float* Wg = (gate == 0) ? Wi : (gate == 1) ? Wf : (gate == 2) ? Wo : Wc;
  const float* Ug = (gate == 0) ? Ui : (gate == 1) ? Uf : (gate == 2) ? Uo : Uc;
  float v = (k < F_) ? Wg[k * H_ + hc] : Ug[(k - F_) * H_ + hc];
  BT[idx] = f2bf(v);
}

__global__ __launch_bounds__(256, 1)
void lstm_persist(const float* __restrict__ x,
                  const unsigned short* __restrict__ BT,
                  const float* __restrict__ bi, const float* __restrict__ bfp,
                  const float* __restrict__ bo, const float* __restrict__ bc,
                  float* __restrict__ out,
                  unsigned* __restrict__ flags,
                  unsigned short* __restrict__ hbuf) {
  __shared__ __align__(16) unsigned short Ash[32][AW];
  __shared__ float Gsh[4][32][18];             // +2 pad: conflict-free scatter

  const int tid = threadIdx.x;
  const int rg = blockIdx.x & 7;     // group (32 rows)
  const int cg = blockIdx.x >> 3;    // 16 h-cols strip (= flag slot)
  const int wave = tid >> 6, lane = tid & 63;
  const int l15 = lane & 15, l4 = lane >> 4;

  // ---- persistent B fragments: wave = gate, 16 cols, full K = 96 VGPRs ----
  short8 Breg[24];
  {
    const unsigned short* Bp =
        BT + (size_t)((wave << 9) | (cg << 4) | l15) * K_ + l4 * 8;
    #pragma unroll
    for (int kk = 0; kk < 24; ++kk)
      Breg[kk] = *reinterpret_cast<const short8*>(Bp + kk * 32);
  }

  // ---- gate-math thread mapping: 2 outputs (row, hc0..hc0+1) ----
  const int grow_r = tid >> 3;             // 0..31
  const int gcol0 = (tid & 7) * 2;         // 0..14 even
  const int hcg = (cg << 4) + gcol0;       // global h col
  const float bi0 = bi[hcg],  bi1 = bi[hcg + 1];
  const float bf0 = bfp[hcg], bf1 = bfp[hcg + 1];
  const float bo0 = bo[hcg],  bo1 = bo[hcg + 1];
  const float bc0 = bc[hcg],  bc1 = bc[hcg + 1];
  float cc0 = 0.f, cc1 = 0.f;              // cell state in registers
  const int grow = rg * 32 + grow_r;
  float* outp = out + (size_t)grow * T_ * H_ + hcg;
  unsigned* hbp0 = reinterpret_cast<unsigned*>(hbuf + (size_t)grow * H_ + hcg);
  unsigned* hbp1 = reinterpret_cast<unsigned*>(hbuf + (size_t)(B_ + grow) * H_ + hcg);

  // ---- stage x(0) ----
  #pragma unroll
  for (int j = 0; j < 8; ++j) {
    int f = tid + 256 * j; int row = f >> 6, k4 = f & 63;
    const float4 v = *reinterpret_cast<const float4*>(
        x + (size_t)(rg * 32 + row) * T_ * F_ + k4 * 4);
    ushort4 s; s.x = f2bf(v.x); s.y = f2bf(v.y); s.z = f2bf(v.z); s.w = f2bf(v.w);
    *reinterpret_cast<ushort4*>(&Ash[row][k4 * 4]) = s;
  }

  unsigned* myflag = flags + (rg * 32 + cg) * 16;
  // this thread's h chunk (cols lane*8..+8) comes entirely from peer lane>>1
  const unsigned* pollflag = flags + (rg * 32 + (lane >> 1)) * 16;
  const unsigned short* hsrc0 = hbuf;                    // parity 0
  const unsigned short* hsrc1 = hbuf + (size_t)B_ * H_;  // parity 1
  const unsigned vo = (unsigned)(((rg * 32 + wave) * H_ + lane * 8) * 2);

  for (int t = 0; t < T_; ++t) {
    // ---- A) per-thread poll source peer, then stage its h(t-1) chunk ----
    if (t > 0) {
      const unsigned want = (unsigned)t;
      unsigned cur;
      do {
        asm volatile("global_load_dword %0, %1, off sc0 sc1\n\ts_waitcnt vmcnt(0)"
                     : "=v"(cur) : "v"(pollflag) : "memory");
      } while (cur < want);
      const unsigned short* hsrc = ((t - 1) & 1) ? hsrc1 : hsrc0;
      short8 h0, h1, h2, h3, h4, h5, h6, h7;
      asm volatile(
        "global_load_dwordx4 %0, %8, %16 sc0 sc1\n\t"
        "global_load_dwordx4 %1, %9, %16 sc0 sc1\n\t"
        "global_load_dwordx4 %2, %10, %16 sc0 sc1\n\t"
        "global_load_dwordx4 %3, %11, %16 sc0 sc1\n\t"
        "global_load_dwordx4 %4, %12, %16 sc0 sc1\n\t"
        "global_load_dwordx4 %5, %13, %16 sc0 sc1\n\t"
        "global_load_dwordx4 %6, %14, %16 sc0 sc1\n\t"
        "global_load_dwordx4 %7, %15, %16 sc0 sc1\n\t"
        "s_waitcnt vmcnt(0)"
        : "=&v"(h0), "=&v"(h1), "=&v"(h2), "=&v"(h3),
          "=&v"(h4), "=&v"(h5), "=&v"(h6), "=&v"(h7)
        : "v"(vo), "v"(vo + 4096u), "v"(vo + 8192u), "v"(vo + 12288u),
          "v"(vo + 16384u), "v"(vo + 20480u), "v"(vo + 24576u), "v"(vo + 28672u),
          "s"(hsrc)
        : "memory");
      *reinterpret_cast<short8*>(&Ash[wave +  0][F_ + lane * 8]) = h0;
      *reinterpret_cast<short8*>(&Ash[wave +  4][F_ + lane * 8]) = h1;
      *reinterpret_cast<short8*>(&Ash[wave +  8][F_ + lane * 8]) = h2;
      *reinterpret_cast<short8*>(&Ash[wave + 12][F_ + lane * 8]) = h3;
      *reinterpret_cast<short8*>(&Ash[wave + 16][F_ + lane * 8]) = h4;
      *reinterpret_cast<short8*>(&Ash[wave + 20][F_ + lane * 8]) = h5;
      *reinterpret_cast<short8*>(&Ash[wave + 24][F_ + lane * 8]) = h6;
      *reinterpret_cast<short8*>(&Ash[wave + 28][F_ + lane * 8]) = h7;
    } else {
      #pragma unroll
      for (int j = 0; j < 8; ++j) {
        int f = tid + 256 * j; int row = f >> 6, c8 = f & 63;
        short8 z = {0, 0, 0, 0, 0, 0, 0, 0};
        *reinterpret_cast<short8*>(&Ash[row][F_ + c8 * 8]) = z;
      }
    }
    __syncthreads();                                   // B1

    // ---- B) issue x(t+1) prefetch (drains during MFMA phase) ----
    float4 xv[8];
    if (t + 1 < T_) {
      #pragma unroll
      for (int j = 0; j < 8; ++j) {
        int f = tid + 256 * j; int row = f >> 6, k4 = f & 63;
        xv[j] = *reinterpret_cast<const float4*>(
            x + ((size_t)(rg * 32 + row) * T_ + (t + 1)) * F_ + k4 * 4);
      }
    }

    // ---- C) MFMA: wave = gate, 32 rows x 16 cols x 768 K ----
    f32x4 acc0 = {0, 0, 0, 0}, acc1 = {0, 0, 0, 0};
    #pragma unroll
    for (int kk = 0; kk < 24; ++kk) {
      const int ks = kk * 32 + l4 * 8;
      const short8 a0 = *reinterpret_cast<const short8*>(&Ash[l15][ks]);
      const short8 a1 = *reinterpret_cast<const short8*>(&Ash[16 + l15][ks]);
      acc0 = __builtin_amdgcn_mfma_f32_16x16x32_bf16(a0, Breg[kk], acc0, 0, 0, 0);
      acc1 = __builtin_amdgcn_mfma_f32_16x16x32_bf16(a1, Breg[kk], acc1, 0, 0, 0);
    }
    #pragma unroll
    for (int r = 0; r < 4; ++r) {                      // D: col=l15, row=l4*4+r
      Gsh[wave][l4 * 4 + r][l15]      = acc0[r];
      Gsh[wave][16 + l4 * 4 + r][l15] = acc1[r];
    }
    __syncthreads();                                   // B2

    // ---- D) gates + cell update; publish h ASAP ----
    float h0, h1;
    {
      const float2 Gi = *reinterpret_cast<const float2*>(&Gsh[0][grow_r][gcol0]);
      const float2 Gf = *reinterpret_cast<const float2*>(&Gsh[1][grow_r][gcol0]);
      const float2 Go = *reinterpret_cast<const float2*>(&Gsh[2][grow_r][gcol0]);
      const float2 Gc = *reinterpret_cast<const float2*>(&Gsh[3][grow_r][gcol0]);
      const float it0 = sigmoid_f(Gi.x + bi0), it1 = sigmoid_f(Gi.y + bi1);
      const float ft0 = sigmoid_f(Gf.x + bf0), ft1 = sigmoid_f(Gf.y + bf1);
      const float ot0 = sigmoid_f(Go.x + bo0), ot1 = sigmoid_f(Go.y + bo1);
      const float ct0 = tanh_f(Gc.x + bc0),    ct1 = tanh_f(Gc.y + bc1);
      cc0 = ft0 * cc0 + it0 * ct0;
      cc1 = ft1 * cc1 + it1 * ct1;
      h0 = ot0 * tanh_f(cc0);
      h1 = ot1 * tanh_f(cc1);
      unsigned hp = (unsigned)f2bf(h0) | ((unsigned)f2bf(h1) << 16);
      unsigned* hq = (t & 1) ? hbp1 : hbp0;            // parity t&1 buffer
      asm volatile("global_store_dword %0, %1, off sc0 sc1"
                   :: "v"(hq), "v"(hp) : "memory");    // bypass -> IF$
    }
    asm volatile("s_waitcnt vmcnt(0)" ::: "memory");   // h store acked at IF$
    __syncthreads();                                   // B3: whole block done
    if (tid == 0) {                                    // publish "step t done"
      unsigned val = (unsigned)(t + 1);
      asm volatile("global_store_dword %0, %1, off sc0 sc1"
                   :: "v"(myflag), "v"(val) : "memory");
    }

    // ---- E) off-chain work: overlaps peer flag propagation ----
    float2 hw; hw.x = h0; hw.y = h1;
    *reinterpret_cast<float2*>(outp + (size_t)t * H_) = hw;
    if (t + 1 < T_) {
      #pragma unroll
      for (int j = 0; j < 8; ++j) {
        int f = tid + 256 * j; int row = f >> 6, k4 = f & 63;
        ushort4 s; s.x = f2bf(xv[j].x); s.y = f2bf(xv[j].y);
        s.z = f2bf(xv[j].z); s.w = f2bf(xv[j].w);
        *reinterpret_cast<ushort4*>(&Ash[row][k4 * 4]) = s;
      }
    }
  }
}

extern "C" void kernel_launch(void* const* d_in, const int* in_sizes, int n_in,
                              void* d_out, int out_size, void* d_ws, size_t ws_size,
                              hipStream_t stream) {
  const float* x  = (const float*)d_in[0];
  const float* Wi = (const float*)d_in[1];
  const float* Ui = (const float*)d_in[2];
  const float* bi = (const float*)d_in[3];
  const float* Wf = (const float*)d_in[4];
  const float* Uf = (const float*)d_in[5];
  const float* bf = (const float*)d_in[6];
  const float* Wc = (const float*)d_in[7];
  const float* Uc = (const float*)d_in[8];
  const float* bc = (const float*)d_in[9];
  const float* Wo = (const float*)d_in[10];
  const float* Uo = (const float*)d_in[11];
  const float* bo = (const float*)d_in[12];
  float* out = (float*)d_out;

  unsigned short* BT = (unsigned short*)d_ws;                          // 3 MB
  unsigned short* hbuf = (unsigned short*)((char*)d_ws + 0x300000);    // 512 KB
  unsigned* flags = (unsigned*)((char*)d_ws + 0x380000);               // 16 KB

  prep_weights<<<(NG_ * K_ + 255) / 256, 256, 0, stream>>>(
      Wi, Wf, Wo, Wc, Ui, Uf, Uo, Uc, BT, flags);

  void* args[] = {(void*)&x, (void*)&BT, (void*)&bi, (void*)&bf, (void*)&bo,
                  (void*)&bc, (void*)&out, (void*)&flags, (void*)&hbuf};
  hipLaunchCooperativeKernel(reinterpret_cast<const void*>(&lstm_persist),
                             dim3(256), dim3(256), args, 0, stream);
}